// Round 9
// baseline (176.897 us; speedup 1.0000x reference)
//
#include <hip/hip_runtime.h>

// MTFNet: N=8, C=8, H=W=256, L=11, SF=2, h=w=128
// Pipeline:
//  K0: xpad[nc][256][272] = column-reflect-padded x (halo 8 each side)
//  K1: E2[n][c'][p] = (blur(x,k) - y), flat reinterpret (p*8+c' = flat(C,h,w)); 4 ps/thread
//  K2: G[n][ki*11+kj][c] = (1/16384)*sum_p window*E2; 704 blocks, direct store (R5-proven)
//  K3: pronet v5: 704 threads, 9 conv steps in ONE rolled loop (single conv-body copy).
//      R8 evidence: v2/v3/v4 all ~50us regardless of wave count -> icache-streaming-bound
//      (9 inlined unrolled copies ~40KB code, cold L1I, 8 CUs). v5 shrinks code ~10x.
// Accounting: harness resets ~95-100us of dur_us — fixed floor.
// R6 lesson: blur/grad are TLP-bound; keep 1024/704 blocks, 4 ps/thread.

__device__ __forceinline__ int refl(int m) {
    m = (m < 0) ? -m : m;
    return (m > 255) ? (510 - m) : m;
}

#define XPROW 272   // 256 + 8 halo each side

// ---------------- K0: column-pad x with reflection ----------------
__global__ __launch_bounds__(256) void pad_kernel(
        const float* __restrict__ x, float* __restrict__ xp) {
    int bid = blockIdx.x;
    int chunk = bid & 3;
    int nc = bid >> 2;
    int team = threadIdx.x >> 6;
    int lane = threadIdx.x & 63;
    const float* xb = x + nc * 65536;
    float* xpb = xp + nc * (256 * XPROW);
    for (int it = 0; it < 16; ++it) {
        int row = chunk * 64 + it * 4 + team;
        const float* src = xb + row * 256;
        float* dst = xpb + row * XPROW + 8;
        float4 v = reinterpret_cast<const float4*>(src)[lane];
        reinterpret_cast<float4*>(dst)[lane] = v;
        if (lane < 8) {
            dst[-1 - lane] = src[1 + lane];
        } else if (lane < 16) {
            int j = lane - 8;
            dst[256 + j] = src[254 - j];
        }
    }
}

// ---------------- K1: blur + subtract y, store transposed E2 (4 ps/thread) --
// grid = 64 nc * 16 rowblk = 1024 blocks, 256 threads (R4/R5 proven config)
__global__ __launch_bounds__(256) void blur_kernel(
        const float* __restrict__ xp, const float* __restrict__ y,
        const float* __restrict__ kk, float* __restrict__ E2) {
    __shared__ float kl[121];
    int bid = blockIdx.x;
    int rowblk = bid & 15;
    int nc = bid >> 4;
    int t = threadIdx.x;
    if (t < 121) kl[t] = kk[nc * 121 + t];
    __syncthreads();
    int r = rowblk * 8 + (t >> 5);
    int ps0 = (t & 31) * 4;
    const float* xb = xp + nc * (256 * XPROW);
    float a0 = 0.f, a1 = 0.f, a2 = 0.f, a3 = 0.f;
    #pragma unroll
    for (int i = 0; i < 11; ++i) {
        int iy = refl(2 * r - 5 + i);
        const float4* row4 = reinterpret_cast<const float4*>(xb + iy * XPROW + 2 * ps0);
        float w[24];
        #pragma unroll
        for (int q = 0; q < 6; ++q) {
            float4 v = row4[q];
            w[4 * q] = v.x; w[4 * q + 1] = v.y; w[4 * q + 2] = v.z; w[4 * q + 3] = v.w;
        }
        #pragma unroll
        for (int j = 0; j < 11; ++j) {
            float kv = kl[i * 11 + j];
            a0 = fmaf(w[j + 3], kv, a0);
            a1 = fmaf(w[j + 5], kv, a1);
            a2 = fmaf(w[j + 7], kv, a2);
            a3 = fmaf(w[j + 9], kv, a3);
        }
    }
    int n = nc >> 3;
    int o = nc * 16384 + r * 128 + ps0;
    float4 yv = *reinterpret_cast<const float4*>(y + o);
    float e[4] = {a0 - yv.x, a1 - yv.y, a2 - yv.z, a3 - yv.w};
    int qn = o - n * 131072;
    int p = qn >> 3;
    int cbase = qn & 7;
    float* eb = E2 + n * 131072 + p;
    #pragma unroll
    for (int qq = 0; qq < 4; ++qq)
        eb[(cbase + qq) * 16384] = e[qq];
}

// ---------------- K2: G contraction (R5-proven: 704 blocks, direct store) ---
__global__ __launch_bounds__(256) void grad_kernel(
        const float* __restrict__ xp, const float* __restrict__ E2,
        float* __restrict__ G) {
    int bid = blockIdx.x;
    int ki = bid % 11;
    int nc = bid / 11;
    int n = nc >> 3, c = nc & 7;
    const float* xb = xp + nc * (256 * XPROW);
    const float* Eb = E2 + n * 131072 + c * 16384;
    int t = threadIdx.x;
    int ps0 = (t & 31) * 4;
    int pr0 = t >> 5;
    float acc[11];
    #pragma unroll
    for (int j = 0; j < 11; ++j) acc[j] = 0.f;
    for (int it = 0; it < 16; ++it) {
        int pr = pr0 + (it << 3);
        int iy = refl(ki + 2 * pr - 5);
        float4 ev = *reinterpret_cast<const float4*>(Eb + pr * 128 + ps0);
        const float4* row4 = reinterpret_cast<const float4*>(xb + iy * XPROW + 2 * ps0);
        float w[24];
        #pragma unroll
        for (int q = 0; q < 6; ++q) {
            float4 v = row4[q];
            w[4 * q] = v.x; w[4 * q + 1] = v.y; w[4 * q + 2] = v.z; w[4 * q + 3] = v.w;
        }
        #pragma unroll
        for (int j = 0; j < 11; ++j) {
            float v = acc[j];
            v = fmaf(w[j + 3], ev.x, v);
            v = fmaf(w[j + 5], ev.y, v);
            v = fmaf(w[j + 7], ev.z, v);
            v = fmaf(w[j + 9], ev.w, v);
            acc[j] = v;
        }
    }
    __shared__ float part[4][11];
    int lane = t & 63, wid = t >> 6;
    #pragma unroll
    for (int j = 0; j < 11; ++j) {
        float v = acc[j];
        #pragma unroll
        for (int off = 32; off > 0; off >>= 1)
            v += __shfl_down(v, off, 64);
        if (lane == 0) part[wid][j] = v;
    }
    __syncthreads();
    if (t < 11) {
        float s = part[0][t] + part[1][t] + part[2][t] + part[3][t];
        G[n * 968 + (ki * 11 + t) * 8 + c] = s * (1.0f / 16384.0f);
    }
}

// ---------------- Fallback kernels (R3, scalar loads, known-good) ----------
__global__ __launch_bounds__(256) void blur_kernel_ref(
        const float* __restrict__ x, const float* __restrict__ y,
        const float* __restrict__ kk, float* __restrict__ E2) {
    __shared__ float kl[121];
    int bid = blockIdx.x;
    int rowblk = bid & 15;
    int nc = bid >> 4;
    int t = threadIdx.x;
    if (t < 121) kl[t] = kk[nc * 121 + t];
    __syncthreads();
    int r = rowblk * 8 + (t >> 5);
    int ps0 = (t & 31) * 4;
    const float* xb = x + nc * 65536;
    float a0 = 0.f, a1 = 0.f, a2 = 0.f, a3 = 0.f;
    int cb = 2 * ps0 - 5;
    #pragma unroll
    for (int i = 0; i < 11; ++i) {
        int iy = refl(2 * r - 5 + i);
        const float* row = xb + iy * 256;
        float c[17];
        #pragma unroll
        for (int u = 0; u < 17; ++u) c[u] = row[refl(cb + u)];
        #pragma unroll
        for (int j = 0; j < 11; ++j) {
            float kv = kl[i * 11 + j];
            a0 = fmaf(c[j], kv, a0);
            a1 = fmaf(c[j + 2], kv, a1);
            a2 = fmaf(c[j + 4], kv, a2);
            a3 = fmaf(c[j + 6], kv, a3);
        }
    }
    int n = nc >> 3;
    int o = nc * 16384 + r * 128 + ps0;
    float4 yv = *reinterpret_cast<const float4*>(y + o);
    float e[4] = {a0 - yv.x, a1 - yv.y, a2 - yv.z, a3 - yv.w};
    int qn = o - n * 131072;
    int p = qn >> 3;
    int cbase = qn & 7;
    float* eb = E2 + n * 131072 + p;
    #pragma unroll
    for (int qq = 0; qq < 4; ++qq)
        eb[(cbase + qq) * 16384] = e[qq];
}

__global__ __launch_bounds__(256) void grad_kernel_ref(
        const float* __restrict__ x, const float* __restrict__ E2,
        float* __restrict__ G) {
    int bid = blockIdx.x;
    int ki = bid % 11;
    int nc = bid / 11;
    int n = nc >> 3, c = nc & 7;
    const float* xb = x + nc * 65536;
    const float* Eb = E2 + n * 131072 + c * 16384;
    int t = threadIdx.x;
    int ps0 = (t & 31) * 4;
    int pr0 = t >> 5;
    int cb = 2 * ps0 - 5;
    float acc[11];
    #pragma unroll
    for (int j = 0; j < 11; ++j) acc[j] = 0.f;
    for (int it = 0; it < 16; ++it) {
        int pr = pr0 + (it << 3);
        int iy = refl(ki + 2 * pr - 5);
        const float* row = xb + iy * 256;
        float cbuf[17];
        #pragma unroll
        for (int u = 0; u < 17; ++u) cbuf[u] = row[refl(cb + u)];
        float4 ev = *reinterpret_cast<const float4*>(Eb + pr * 128 + ps0);
        #pragma unroll
        for (int j = 0; j < 11; ++j) {
            float v = acc[j];
            v = fmaf(cbuf[j], ev.x, v);
            v = fmaf(cbuf[j + 2], ev.y, v);
            v = fmaf(cbuf[j + 4], ev.z, v);
            v = fmaf(cbuf[j + 6], ev.w, v);
            acc[j] = v;
        }
    }
    __shared__ float part[4][11];
    int lane = t & 63, wid = t >> 6;
    #pragma unroll
    for (int j = 0; j < 11; ++j) {
        float v = acc[j];
        #pragma unroll
        for (int off = 32; off > 0; off >>= 1)
            v += __shfl_down(v, off, 64);
        if (lane == 0) part[wid][j] = v;
    }
    __syncthreads();
    if (t < 11) {
        float s = part[0][t] + part[1][t] + part[2][t] + part[3][t];
        G[n * 968 + (ki * 11 + t) * 8 + c] = s * (1.0f / 16384.0f);
    }
}

// ---------------- K3: pronet v5 — rolled steps, single conv-body copy ------
// 704 threads = 11 waves: g = t/88 picks ci (0..7), id = t%88 -> (co, yy).
// Steps 0..8 in a runtime loop; Pin/mode are wave-uniform selects.
// NOTE: launch MUST be 704 threads (== __launch_bounds__); mismatch no-ops (R2).
struct PArgs {
    const float* W[9];
    const float* B[9];
    const float* k;
    const float* gamma;
    const float* G;
    float* out;
};

#define PLSTRIDE 20
#define WSTRIDE 12

__global__ __launch_bounds__(704) void pronet_kernel(PArgs pa) {
    __shared__ __align__(16) float P0[8 * 13 * PLSTRIDE];
    __shared__ __align__(16) float P1[8 * 13 * PLSTRIDE];
    __shared__ float G2[968];
    __shared__ float F[968];
    __shared__ __align__(16) float red[7 * 88 * WSTRIDE];
    __shared__ __align__(16) float wts[9 * 64 * WSTRIDE];
    __shared__ float bs[9 * 8];
    __shared__ float rowsum[88];
    __shared__ float inv[8];

    int n = blockIdx.x;
    int t = threadIdx.x;

    // stage weights padded (rolled): wts[(widx*64 + oc)*12 + q] = W[widx][oc*9 + q]
    for (int widx = 0; widx < 9; ++widx) {
        const float* wsrc = pa.W[widx];
        if (t < 576) {
            int oc = t / 9, q = t - oc * 9;
            wts[(widx * 64 + oc) * WSTRIDE + q] = wsrc[t];
        }
        if (t < 8) bs[widx * 8 + t] = pa.B[widx][t];
    }
    for (int i = t; i < 8 * 13 * PLSTRIDE; i += 704) { P0[i] = 0.f; P1[i] = 0.f; }
    __syncthreads();

    float gm = pa.gamma[0] * 0.1f;
    for (int o = t; o < 968; o += 704) {
        // G_K flat reinterpretation: elementwise in flat order
        float v = pa.k[n * 968 + o] - gm * pa.G[n * 968 + o];
        G2[o] = v;
        int co = o / 121, rem = o - co * 121;
        int yy = rem / 11, xx = rem - yy * 11;
        P0[(co * 13 + yy + 1) * PLSTRIDE + xx + 1] = v;
    }

    int g = t / 88;              // ci group 0..7
    int id = t - g * 88;         // 0..87
    int co = id / 11, yy = id - co * 11;
    int ci = g;

    // steps: 0,2,4,6 -> mode0 (P0 conv -> P1); 1,3,5,7 -> mode1 (P1 conv,
    // residual into P0); 8 -> mode2 (P0 conv, final into F). ONE body copy.
    for (int step = 0; step < 9; ++step) {
        int mode = (step == 8) ? 2 : (step & 1);
        const float* Pin = (mode == 1) ? P1 : P0;
        int widx = step;
        __syncthreads();
        float acc[12];
        {
            const float4* wp4 = reinterpret_cast<const float4*>(
                &wts[(widx * 64 + co * 8 + ci) * WSTRIDE]);
            float4 w0 = wp4[0], w1 = wp4[1], w2 = wp4[2];
            float wv[9] = {w0.x, w0.y, w0.z, w0.w, w1.x, w1.y, w1.z, w1.w, w2.x};
            float r[3][13];
            #pragma unroll
            for (int dy = 0; dy < 3; ++dy) {
                const float* row = Pin + (ci * 13 + yy + dy) * PLSTRIDE;
                float4 a = *reinterpret_cast<const float4*>(row);
                float4 b = *reinterpret_cast<const float4*>(row + 4);
                float4 c = *reinterpret_cast<const float4*>(row + 8);
                r[dy][0] = a.x;  r[dy][1] = a.y;  r[dy][2]  = a.z;  r[dy][3]  = a.w;
                r[dy][4] = b.x;  r[dy][5] = b.y;  r[dy][6]  = b.z;  r[dy][7]  = b.w;
                r[dy][8] = c.x;  r[dy][9] = c.y;  r[dy][10] = c.z;  r[dy][11] = c.w;
                r[dy][12] = row[12];
            }
            #pragma unroll
            for (int xx = 0; xx < 11; ++xx) {
                float v = 0.f;
                v = fmaf(r[0][xx],     wv[0], v);
                v = fmaf(r[0][xx + 1], wv[1], v);
                v = fmaf(r[0][xx + 2], wv[2], v);
                v = fmaf(r[1][xx],     wv[3], v);
                v = fmaf(r[1][xx + 1], wv[4], v);
                v = fmaf(r[1][xx + 2], wv[5], v);
                v = fmaf(r[2][xx],     wv[6], v);
                v = fmaf(r[2][xx + 1], wv[7], v);
                v = fmaf(r[2][xx + 2], wv[8], v);
                acc[xx] = v;
            }
            acc[11] = 0.f;
            if (g != 0) {
                float4* rp = reinterpret_cast<float4*>(
                    &red[((g - 1) * 88 + id) * WSTRIDE]);
                rp[0] = make_float4(acc[0], acc[1], acc[2],  acc[3]);
                rp[1] = make_float4(acc[4], acc[5], acc[6],  acc[7]);
                rp[2] = make_float4(acc[8], acc[9], acc[10], acc[11]);
            }
        }
        __syncthreads();
        if (g == 0) {
            float b = bs[widx * 8 + co];
            float oth[12];
            #pragma unroll
            for (int pq = 0; pq < 7; ++pq) {
                const float4* rp = reinterpret_cast<const float4*>(
                    &red[(pq * 88 + id) * WSTRIDE]);
                float4 v0 = rp[0], v1 = rp[1], v2 = rp[2];
                if (pq == 0) {
                    oth[0] = v0.x; oth[1] = v0.y; oth[2]  = v0.z; oth[3]  = v0.w;
                    oth[4] = v1.x; oth[5] = v1.y; oth[6]  = v1.z; oth[7]  = v1.w;
                    oth[8] = v2.x; oth[9] = v2.y; oth[10] = v2.z; oth[11] = v2.w;
                } else {
                    oth[0] += v0.x; oth[1] += v0.y; oth[2]  += v0.z; oth[3]  += v0.w;
                    oth[4] += v1.x; oth[5] += v1.y; oth[6]  += v1.z; oth[7]  += v1.w;
                    oth[8] += v2.x; oth[9] += v2.y; oth[10] += v2.z; oth[11] += v2.w;
                }
            }
            #pragma unroll
            for (int xx = 0; xx < 11; ++xx) {
                float v = acc[xx] + oth[xx] + b;
                int pidx = (co * 13 + yy + 1) * PLSTRIDE + xx + 1;
                if (mode == 0) {
                    P1[pidx] = fmaxf(v, 0.f);
                } else if (mode == 1) {
                    float p = P0[pidx];
                    P0[pidx] = fmaxf(fmaf(0.1f, v, p), 0.f);
                } else {
                    int fo = co * 121 + yy * 11 + xx;
                    F[fo] = fmaxf(fmaf(0.1f, v, G2[fo]), 0.f);
                }
            }
        }
    }
    __syncthreads();

    if (t < 88) {
        int tco = t / 11, tyy = t - tco * 11;
        float s = 0.f;
        #pragma unroll
        for (int xx = 0; xx < 11; ++xx) s += F[tco * 121 + tyy * 11 + xx];
        rowsum[t] = s;
    }
    __syncthreads();
    if (t < 8) {
        float s = 0.f;
        #pragma unroll
        for (int j = 0; j < 11; ++j) s += rowsum[t * 11 + j];
        inv[t] = 1.f / s;
    }
    __syncthreads();
    for (int o = t; o < 968; o += 704)
        pa.out[n * 968 + o] = F[o] * inv[o / 121];
}

extern "C" void kernel_launch(void* const* d_in, const int* in_sizes, int n_in,
                              void* d_out, int out_size, void* d_ws, size_t ws_size,
                              hipStream_t stream) {
    const float* x = (const float*)d_in[0];
    const float* y = (const float*)d_in[1];
    const float* k = (const float*)d_in[2];
    const float* gamma = (const float*)d_in[4];

    const size_t xpad_fl = (size_t)64 * 256 * XPROW;
    const size_t e2_fl = (size_t)8 * 131072;
    const size_t need = (xpad_fl + e2_fl + 7744) * sizeof(float);

    float* G;
    if (ws_size >= need) {
        float* xpad = (float*)d_ws;
        float* E2 = xpad + xpad_fl;
        G = E2 + e2_fl;
        pad_kernel<<<256, 256, 0, stream>>>(x, xpad);
        blur_kernel<<<1024, 256, 0, stream>>>(xpad, y, k, E2);
        grad_kernel<<<704, 256, 0, stream>>>(xpad, E2, G);
    } else {
        float* E2 = (float*)d_ws;
        G = E2 + e2_fl;
        blur_kernel_ref<<<1024, 256, 0, stream>>>(x, y, k, E2);
        grad_kernel_ref<<<704, 256, 0, stream>>>(x, E2, G);
    }

    PArgs pa;
    for (int i = 0; i < 9; ++i) {
        pa.W[i] = (const float*)d_in[5 + 2 * i];
        pa.B[i] = (const float*)d_in[6 + 2 * i];
    }
    pa.k = k;
    pa.gamma = gamma;
    pa.G = G;
    pa.out = (float*)d_out;
    pronet_kernel<<<8, 704, 0, stream>>>(pa);
}